// Round 1
// baseline (208.807 us; speedup 1.0000x reference)
//
#include <hip/hip_runtime.h>
#include <hip/hip_bf16.h>
#include <stdint.h>

// Problem constants (SelfAttentionHead): B=8, T=2048, E=1024, D=128
#define Bq 8
#define Tq 2048
#define Eq 1024
#define Dq 128

typedef __attribute__((ext_vector_type(8))) short short8;   // 8 x bf16 (4 VGPR) MFMA frag
typedef __attribute__((ext_vector_type(4))) float f32x4;    // MFMA accumulator

__device__ __forceinline__ unsigned short f2b(float f) {
  __hip_bfloat16 h = __float2bfloat16(f);   // RNE
  return __builtin_bit_cast(unsigned short, h);
}

// ---------------- cast x: fp32 -> bf16, vectorized ----------------
__global__ void cast_x_kernel(const float* __restrict__ x,
                              unsigned short* __restrict__ xb, int n4) {
  int stride = gridDim.x * blockDim.x;
  for (int i = blockIdx.x * blockDim.x + threadIdx.x; i < n4; i += stride) {
    float4 f = reinterpret_cast<const float4*>(x)[i];
    ushort4 u;
    u.x = f2b(f.x); u.y = f2b(f.y); u.z = f2b(f.z); u.w = f2b(f.w);
    reinterpret_cast<ushort4*>(xb)[i] = u;
  }
}

// ------------- weights: transpose + cast -> wt[p][d][e] = W_p[e][d] -------------
// p order: 0=Wq, 1=Wk, 2=Wv
__global__ void prep_w_kernel(const float* __restrict__ wq, const float* __restrict__ wk,
                              const float* __restrict__ wv, unsigned short* __restrict__ wt) {
  int stride = gridDim.x * blockDim.x;
  const int total = 3 * Dq * Eq;
  for (int o = blockIdx.x * blockDim.x + threadIdx.x; o < total; o += stride) {
    int p = o / (Dq * Eq);
    int r = o - p * (Dq * Eq);
    int d = r / Eq;
    int e = r - d * Eq;
    const float* w = (p == 0) ? wq : (p == 1) ? wk : wv;
    wt[o] = f2b(w[e * Dq + d]);
  }
}

// ------------- projection GEMM: [16384 x 1024] @ Wt^T -> q/k (row-major), vT ([B][D][T]) -------------
// 128x128 tile, 4 waves as 2x2 (each wave 64x64 = 4x4 frags of 16x16), BK=32.
// A and B fragments loaded directly from global (x streamed once, Wt is L2-resident).
__global__ __launch_bounds__(256) void proj_kernel(const unsigned short* __restrict__ xb,
                                                   const unsigned short* __restrict__ wt,
                                                   unsigned short* __restrict__ qo,
                                                   unsigned short* __restrict__ ko,
                                                   unsigned short* __restrict__ vo) {
  const int p    = blockIdx.y;            // 0=q 1=k 2=v
  const int lane = threadIdx.x & 63;
  const int wid  = threadIdx.x >> 6;
  const int wm   = wid >> 1, wn = wid & 1;
  const int row0 = blockIdx.x * 128 + wm * 64;
  const int col0 = wn * 64;
  const int lrow = lane & 15;
  const int lk8  = (lane >> 4) * 8;       // A/B frag: 8 contiguous k-elements
  const unsigned short* wtp = wt + p * (Dq * Eq);

  f32x4 acc[4][4];
#pragma unroll
  for (int m = 0; m < 4; ++m)
#pragma unroll
    for (int n = 0; n < 4; ++n) acc[m][n] = (f32x4){0.f, 0.f, 0.f, 0.f};

  for (int ks = 0; ks < Eq; ks += 32) {
    short8 a[4], b[4];
#pragma unroll
    for (int m = 0; m < 4; ++m)
      a[m] = *reinterpret_cast<const short8*>(xb + (size_t)(row0 + m * 16 + lrow) * Eq + ks + lk8);
#pragma unroll
    for (int n = 0; n < 4; ++n)
      b[n] = *reinterpret_cast<const short8*>(wtp + (size_t)(col0 + n * 16 + lrow) * Eq + ks + lk8);
#pragma unroll
    for (int m = 0; m < 4; ++m)
#pragma unroll
      for (int n = 0; n < 4; ++n)
        acc[m][n] = __builtin_amdgcn_mfma_f32_16x16x32_bf16(a[m], b[n], acc[m][n], 0, 0, 0);
  }

  // epilogue: C/D layout col=lane&15, row=(lane>>4)*4+reg  [verified m89/m91]
  const int rg   = (lane >> 4) * 4;
  const int lcol = lane & 15;
  if (p < 2) {
    unsigned short* out = (p == 0) ? qo : ko;
#pragma unroll
    for (int m = 0; m < 4; ++m)
#pragma unroll
      for (int n = 0; n < 4; ++n)
#pragma unroll
        for (int r = 0; r < 4; ++r)
          out[(size_t)(row0 + m * 16 + rg + r) * Dq + col0 + n * 16 + lcol] = f2b(acc[m][n][r]);
  } else {
    // store V transposed: vT[b][d][t]
#pragma unroll
    for (int m = 0; m < 4; ++m)
#pragma unroll
      for (int n = 0; n < 4; ++n)
#pragma unroll
        for (int r = 0; r < 4; ++r) {
          int trow = row0 + m * 16 + rg + r;
          int bb = trow >> 11;            // /T
          int t  = trow & (Tq - 1);
          vo[(size_t)bb * Dq * Tq + (size_t)(col0 + n * 16 + lcol) * Tq + t] = f2b(acc[m][n][r]);
        }
  }
}

// ------------- causal flash attention -------------
// 1 wave handles a 16-row Q tile; each wave processes the complementary pair
// (tile j, tile 127-j) within its batch -> uniform ~65 KV steps per wave.
// 512 waves = 256 blocks x 2 waves.
__global__ __launch_bounds__(128) void attn_kernel(const unsigned short* __restrict__ q,
                                                   const unsigned short* __restrict__ k,
                                                   const unsigned short* __restrict__ vT,
                                                   float* __restrict__ out) {
  __shared__ __align__(16) unsigned short pbuf[2][16 * 32];  // per-wave P tile (bf16)
  const int lane = threadIdx.x & 63;
  const int wid  = threadIdx.x >> 6;
  const int w    = blockIdx.x * 2 + wid;   // 0..511
  const int b    = w >> 6;                 // batch
  const int j    = w & 63;                 // tile pair index
  const int lrow = lane & 15;
  const int lgrp = lane >> 4;
  const int lk8  = lgrp * 8;
  // fold softmax scale and log2(e) into the score scale; use exp2
  const float kscale = 0.08838834764831845f * 1.44269504088896340736f;
  unsigned short* pb = pbuf[wid];

  for (int which = 0; which < 2; ++which) {
    const int tile = which ? (127 - j) : j;
    const int qb0  = tile * 16;

    short8 qf[4];
    const unsigned short* qrow = q + ((size_t)b * Tq + qb0 + lrow) * Dq;
#pragma unroll
    for (int kc = 0; kc < 4; ++kc)
      qf[kc] = *reinterpret_cast<const short8*>(qrow + kc * 32 + lk8);

    f32x4 o[8];
#pragma unroll
    for (int n = 0; n < 8; ++n) o[n] = (f32x4){0.f, 0.f, 0.f, 0.f};
    float m[4], l[4];
#pragma unroll
    for (int r = 0; r < 4; ++r) { m[r] = -1e30f; l[r] = 0.f; }

    const int rowg = qb0 + lgrp * 4;       // + reg -> global q row of score element

    for (int kvb = 0; kvb < qb0 + 16; kvb += 32) {
      // ---- QK^T : scores for cols [kvb, kvb+32) ----
      f32x4 s0 = (f32x4){0.f, 0.f, 0.f, 0.f};
      f32x4 s1 = (f32x4){0.f, 0.f, 0.f, 0.f};
      const unsigned short* kb = k + ((size_t)b * Tq + kvb) * Dq;
#pragma unroll
      for (int kc = 0; kc < 4; ++kc) {
        short8 k0 = *reinterpret_cast<const short8*>(kb + (size_t)lrow * Dq + kc * 32 + lk8);
        short8 k1 = *reinterpret_cast<const short8*>(kb + (size_t)(16 + lrow) * Dq + kc * 32 + lk8);
        s0 = __builtin_amdgcn_mfma_f32_16x16x32_bf16(qf[kc], k0, s0, 0, 0, 0);
        s1 = __builtin_amdgcn_mfma_f32_16x16x32_bf16(qf[kc], k1, s1, 0, 0, 0);
      }

      // ---- scale + causal mask (only tiles crossing the diagonal) ----
      float p0[4], p1[4], mx[4];
      const bool needmask = (kvb + 32 > qb0);
      const int col0 = kvb + lrow;
#pragma unroll
      for (int r = 0; r < 4; ++r) {
        float a0 = s0[r] * kscale, a1 = s1[r] * kscale;
        if (needmask) {
          if (col0 > rowg + r)      a0 = -1e30f;
          if (col0 + 16 > rowg + r) a1 = -1e30f;
        }
        p0[r] = a0; p1[r] = a1; mx[r] = fmaxf(a0, a1);
      }
      // row max across the 16 lanes holding this row's columns
#pragma unroll
      for (int off = 1; off < 16; off <<= 1)
#pragma unroll
        for (int r = 0; r < 4; ++r) mx[r] = fmaxf(mx[r], __shfl_xor(mx[r], off, 64));

      float alpha[4], sm[4];
#pragma unroll
      for (int r = 0; r < 4; ++r) {
        float mn = fmaxf(m[r], mx[r]);
        alpha[r] = exp2f(m[r] - mn);
        m[r] = mn;
        p0[r] = exp2f(p0[r] - mn);
        p1[r] = exp2f(p1[r] - mn);
        sm[r] = p0[r] + p1[r];
      }
#pragma unroll
      for (int off = 1; off < 16; off <<= 1)
#pragma unroll
        for (int r = 0; r < 4; ++r) sm[r] += __shfl_xor(sm[r], off, 64);
#pragma unroll
      for (int r = 0; r < 4; ++r) l[r] = l[r] * alpha[r] + sm[r];
#pragma unroll
      for (int n = 0; n < 8; ++n)
#pragma unroll
        for (int r = 0; r < 4; ++r) o[n][r] *= alpha[r];

      // ---- P (score layout) -> LDS -> A-operand fragment layout ----
#pragma unroll
      for (int r = 0; r < 4; ++r) {
        pb[(lgrp * 4 + r) * 32 + lrow]      = f2b(p0[r]);
        pb[(lgrp * 4 + r) * 32 + 16 + lrow] = f2b(p1[r]);
      }
      asm volatile("s_waitcnt lgkmcnt(0)" ::: "memory");
      __builtin_amdgcn_sched_barrier(0);
      short8 pf = *reinterpret_cast<const short8*>(pb + lrow * 32 + lk8);

      // ---- PV: O += P @ V  (V read from transposed layout, contiguous in k) ----
      const unsigned short* vb = vT + (size_t)b * Dq * Tq + kvb;
#pragma unroll
      for (int n = 0; n < 8; ++n) {
        short8 vf = *reinterpret_cast<const short8*>(vb + (size_t)(n * 16 + lrow) * Tq + lk8);
        o[n] = __builtin_amdgcn_mfma_f32_16x16x32_bf16(pf, vf, o[n], 0, 0, 0);
      }
    }

    // ---- epilogue: out fp32 [B,T,D] ----
    float inv[4];
#pragma unroll
    for (int r = 0; r < 4; ++r) inv[r] = 1.0f / l[r];
    float* ob = out + ((size_t)b * Tq + qb0) * Dq;
#pragma unroll
    for (int n = 0; n < 8; ++n)
#pragma unroll
      for (int r = 0; r < 4; ++r)
        ob[(size_t)(lgrp * 4 + r) * Dq + n * 16 + lrow] = o[n][r] * inv[r];
  }
}

extern "C" void kernel_launch(void* const* d_in, const int* in_sizes, int n_in,
                              void* d_out, int out_size, void* d_ws, size_t ws_size,
                              hipStream_t stream) {
  // setup_inputs order: x, Wk, Wq, Wv
  const float* x  = (const float*)d_in[0];
  const float* Wk = (const float*)d_in[1];
  const float* Wq = (const float*)d_in[2];
  const float* Wv = (const float*)d_in[3];
  float* out = (float*)d_out;

  // workspace layout (bf16 elements): x | Wt[3][D][E] | q | k | vT   (~47 MB)
  unsigned short* xb = (unsigned short*)d_ws;
  unsigned short* wt = xb + (size_t)Bq * Tq * Eq;
  unsigned short* qb = wt + (size_t)3 * Dq * Eq;
  unsigned short* kb = qb + (size_t)Bq * Tq * Dq;
  unsigned short* vb = kb + (size_t)Bq * Tq * Dq;

  cast_x_kernel<<<2048, 256, 0, stream>>>(x, xb, Bq * Tq * Eq / 4);
  prep_w_kernel<<<512, 256, 0, stream>>>(Wq, Wk, Wv, wt);
  proj_kernel<<<dim3(Bq * Tq / 128, 3), 256, 0, stream>>>(xb, wt, qb, kb, vb);
  attn_kernel<<<256, 128, 0, stream>>>(qb, kb, vb, out);
}

// Round 2
// 204.725 us; speedup vs baseline: 1.0199x; 1.0199x over previous
//
#include <hip/hip_runtime.h>
#include <hip/hip_bf16.h>
#include <stdint.h>

// Problem constants (SelfAttentionHead): B=8, T=2048, E=1024, D=128
#define Bq 8
#define Tq 2048
#define Eq 1024
#define Dq 128
#define LSEG 256                 // KV positions per split-KV segment
#define SLOTS_PER_B 576          // sum_j ceil((16j+16)/256) = 16*(1+...+8)
#define NSLOT (Bq * SLOTS_PER_B) // 4608

typedef __attribute__((ext_vector_type(8))) short short8;   // 8 x bf16 (4 VGPR) MFMA frag
typedef __attribute__((ext_vector_type(4))) float f32x4;    // MFMA accumulator

__device__ __forceinline__ unsigned short f2b(float f) {
  __hip_bfloat16 h = __float2bfloat16(f);   // RNE
  return __builtin_bit_cast(unsigned short, h);
}
__device__ __forceinline__ float b2f(unsigned short u) {
  unsigned int x = ((unsigned int)u) << 16;
  return __builtin_bit_cast(float, x);
}

// ---------------- cast x: fp32 -> bf16, vectorized ----------------
__global__ void cast_x_kernel(const float* __restrict__ x,
                              unsigned short* __restrict__ xb, int n4) {
  int stride = gridDim.x * blockDim.x;
  for (int i = blockIdx.x * blockDim.x + threadIdx.x; i < n4; i += stride) {
    float4 f = reinterpret_cast<const float4*>(x)[i];
    ushort4 u;
    u.x = f2b(f.x); u.y = f2b(f.y); u.z = f2b(f.z); u.w = f2b(f.w);
    reinterpret_cast<ushort4*>(xb)[i] = u;
  }
}

// ------------- weights: transpose + cast -> wt[p][d][e] = W_p[e][d] -------------
__global__ void prep_w_kernel(const float* __restrict__ wq, const float* __restrict__ wk,
                              const float* __restrict__ wv, unsigned short* __restrict__ wt) {
  int stride = gridDim.x * blockDim.x;
  const int total = 3 * Dq * Eq;
  for (int o = blockIdx.x * blockDim.x + threadIdx.x; o < total; o += stride) {
    int p = o / (Dq * Eq);
    int r = o - p * (Dq * Eq);
    int d = r / Eq;
    int e = r - d * Eq;
    const float* w = (p == 0) ? wq : (p == 1) ? wk : wv;
    wt[o] = f2b(w[e * Dq + d]);
  }
}

// ------------- projection GEMM -> q/k (row-major), vT ([B][D][T]) -------------
// 64x128 tile, 4 waves as 2x2 (wave = 32x64 = 2x4 frags), BK=32. 768 blocks.
__global__ __launch_bounds__(256) void proj_kernel(const unsigned short* __restrict__ xb,
                                                   const unsigned short* __restrict__ wt,
                                                   unsigned short* __restrict__ qo,
                                                   unsigned short* __restrict__ ko,
                                                   unsigned short* __restrict__ vo) {
  const int p    = blockIdx.y;            // 0=q 1=k 2=v
  const int lane = threadIdx.x & 63;
  const int wid  = threadIdx.x >> 6;
  const int wm   = wid >> 1, wn = wid & 1;
  const int row0 = blockIdx.x * 64 + wm * 32;
  const int col0 = wn * 64;
  const int lrow = lane & 15;
  const int lk8  = (lane >> 4) * 8;
  const unsigned short* wtp = wt + p * (Dq * Eq);

  f32x4 acc[2][4];
#pragma unroll
  for (int m = 0; m < 2; ++m)
#pragma unroll
    for (int n = 0; n < 4; ++n) acc[m][n] = (f32x4){0.f, 0.f, 0.f, 0.f};

  for (int ks = 0; ks < Eq; ks += 32) {
    short8 a[2], b[4];
#pragma unroll
    for (int m = 0; m < 2; ++m)
      a[m] = *reinterpret_cast<const short8*>(xb + (size_t)(row0 + m * 16 + lrow) * Eq + ks + lk8);
#pragma unroll
    for (int n = 0; n < 4; ++n)
      b[n] = *reinterpret_cast<const short8*>(wtp + (size_t)(col0 + n * 16 + lrow) * Eq + ks + lk8);
#pragma unroll
    for (int m = 0; m < 2; ++m)
#pragma unroll
      for (int n = 0; n < 4; ++n)
        acc[m][n] = __builtin_amdgcn_mfma_f32_16x16x32_bf16(a[m], b[n], acc[m][n], 0, 0, 0);
  }

  const int rg   = (lane >> 4) * 4;
  const int lcol = lane & 15;
  if (p < 2) {
    unsigned short* out = (p == 0) ? qo : ko;
#pragma unroll
    for (int m = 0; m < 2; ++m)
#pragma unroll
      for (int n = 0; n < 4; ++n)
#pragma unroll
        for (int r = 0; r < 4; ++r)
          out[(size_t)(row0 + m * 16 + rg + r) * Dq + col0 + n * 16 + lcol] = f2b(acc[m][n][r]);
  } else {
#pragma unroll
    for (int m = 0; m < 2; ++m)
#pragma unroll
      for (int n = 0; n < 4; ++n)
#pragma unroll
        for (int r = 0; r < 4; ++r) {
          int trow = row0 + m * 16 + rg + r;
          int bb = trow >> 11;
          int t  = trow & (Tq - 1);
          vo[(size_t)bb * Dq * Tq + (size_t)(col0 + n * 16 + lcol) * Tq + t] = f2b(acc[m][n][r]);
        }
  }
}

// ------------- split-KV causal flash attention -------------
// Wave = (batch b, 16-row Q tile j, KV segment s of LSEG=256). nseg(j)=j/16+1.
// 4608 waves (4.5/SIMD). KV step = 64 cols. Partials: O bf16 + m,l f32.
__global__ __launch_bounds__(256) void attn_kernel(const unsigned short* __restrict__ q,
                                                   const unsigned short* __restrict__ k,
                                                   const unsigned short* __restrict__ vT,
                                                   unsigned short* __restrict__ pO,
                                                   float* __restrict__ pm,
                                                   float* __restrict__ pl) {
  __shared__ __align__(16) unsigned short pbuf[4][16 * 64];  // per-wave P tile
  const int lane = threadIdx.x & 63;
  const int wid  = threadIdx.x >> 6;
  const int w    = blockIdx.x * 4 + wid;   // 0..4607 == slot id
  const int b    = w / SLOTS_PER_B;
  int rm = w - b * SLOTS_PER_B;
  // invert slot -> (group a, tile-in-group r, segment s)
  int a = 0, rr_t = 0, s = 0;
#pragma unroll
  for (int g = 0; g < 8; ++g) {
    int cnt = 16 * (g + 1);
    if (rm < cnt) { a = g; rr_t = rm / (g + 1); s = rm % (g + 1); break; }
    rm -= cnt;
  }
  const int j    = a * 16 + rr_t;
  const int qb0  = j * 16;
  const int kv0  = s * LSEG;
  const int kend = min(kv0 + LSEG, qb0 + 16);

  const int lrow = lane & 15;
  const int lgrp = lane >> 4;
  const int lk8  = lgrp * 8;
  const float kscale = 0.08838834764831845f * 1.44269504088896340736f; // D^-0.5 * log2(e)
  unsigned short* pb = pbuf[wid];

  short8 qf[4];
  const unsigned short* qrow = q + ((size_t)b * Tq + qb0 + lrow) * Dq;
#pragma unroll
  for (int kc = 0; kc < 4; ++kc)
    qf[kc] = *reinterpret_cast<const short8*>(qrow + kc * 32 + lk8);

  f32x4 o[8];
#pragma unroll
  for (int n = 0; n < 8; ++n) o[n] = (f32x4){0.f, 0.f, 0.f, 0.f};
  float m[4], l[4];
#pragma unroll
  for (int r = 0; r < 4; ++r) { m[r] = -1e30f; l[r] = 0.f; }
  const int rowg = qb0 + lgrp * 4;

  for (int kvb = kv0; kvb < kend; kvb += 64) {
    // ---- QK^T: 64 score cols ----
    f32x4 sf[4];
#pragma unroll
    for (int n = 0; n < 4; ++n) sf[n] = (f32x4){0.f, 0.f, 0.f, 0.f};
    const unsigned short* kb = k + ((size_t)b * Tq + kvb) * Dq;
#pragma unroll
    for (int kc = 0; kc < 4; ++kc)
#pragma unroll
      for (int n = 0; n < 4; ++n) {
        short8 kf = *reinterpret_cast<const short8*>(kb + (size_t)(n * 16 + lrow) * Dq + kc * 32 + lk8);
        sf[n] = __builtin_amdgcn_mfma_f32_16x16x32_bf16(qf[kc], kf, sf[n], 0, 0, 0);
      }

    // ---- scale + causal mask + online softmax ----
    const bool needmask = (kvb + 64 > qb0);
    float p[4][4], mx[4];
#pragma unroll
    for (int r = 0; r < 4; ++r) mx[r] = -1e30f;
#pragma unroll
    for (int n = 0; n < 4; ++n)
#pragma unroll
      for (int r = 0; r < 4; ++r) {
        float aa = sf[n][r] * kscale;
        if (needmask && (kvb + n * 16 + lrow > rowg + r)) aa = -1e30f;
        p[n][r] = aa;
        mx[r] = fmaxf(mx[r], aa);
      }
#pragma unroll
    for (int off = 1; off < 16; off <<= 1)
#pragma unroll
      for (int r = 0; r < 4; ++r) mx[r] = fmaxf(mx[r], __shfl_xor(mx[r], off, 64));

    float alpha[4], sm[4];
#pragma unroll
    for (int r = 0; r < 4; ++r) {
      float mn = fmaxf(m[r], mx[r]);
      alpha[r] = exp2f(m[r] - mn);
      m[r] = mn;
      sm[r] = 0.f;
#pragma unroll
      for (int n = 0; n < 4; ++n) {
        p[n][r] = exp2f(p[n][r] - mn);
        sm[r] += p[n][r];
      }
    }
#pragma unroll
    for (int off = 1; off < 16; off <<= 1)
#pragma unroll
      for (int r = 0; r < 4; ++r) sm[r] += __shfl_xor(sm[r], off, 64);
#pragma unroll
    for (int r = 0; r < 4; ++r) l[r] = l[r] * alpha[r] + sm[r];
#pragma unroll
    for (int n = 0; n < 8; ++n)
#pragma unroll
      for (int r = 0; r < 4; ++r) o[n][r] *= alpha[r];

    // ---- P -> LDS (XOR-swizzled) -> A-operand fragments ----
#pragma unroll
    for (int n = 0; n < 4; ++n)
#pragma unroll
      for (int r = 0; r < 4; ++r) {
        int row = lgrp * 4 + r;
        int byte = row * 128 + (n * 16 + lrow) * 2;
        byte ^= (row & 7) << 4;
        *reinterpret_cast<unsigned short*>(reinterpret_cast<char*>(pb) + byte) = f2b(p[n][r]);
      }
    asm volatile("s_waitcnt lgkmcnt(0)" ::: "memory");
    __builtin_amdgcn_sched_barrier(0);
    int rbyte0 = (lrow * 128 + lgrp * 16) ^ ((lrow & 7) << 4);
    int rbyte1 = (lrow * 128 + 64 + lgrp * 16) ^ ((lrow & 7) << 4);
    short8 pf0 = *reinterpret_cast<const short8*>(reinterpret_cast<char*>(pb) + rbyte0);
    short8 pf1 = *reinterpret_cast<const short8*>(reinterpret_cast<char*>(pb) + rbyte1);

    // ---- PV: O += P @ V ----
    const unsigned short* vb = vT + (size_t)b * Dq * Tq + kvb;
#pragma unroll
    for (int n = 0; n < 8; ++n) {
      short8 vf0 = *reinterpret_cast<const short8*>(vb + (size_t)(n * 16 + lrow) * Tq + lk8);
      short8 vf1 = *reinterpret_cast<const short8*>(vb + (size_t)(n * 16 + lrow) * Tq + 32 + lk8);
      o[n] = __builtin_amdgcn_mfma_f32_16x16x32_bf16(pf0, vf0, o[n], 0, 0, 0);
      o[n] = __builtin_amdgcn_mfma_f32_16x16x32_bf16(pf1, vf1, o[n], 0, 0, 0);
    }
  }

  // ---- store partial (unnormalized O in bf16, running m/l in f32) ----
  unsigned short* po = pO + (size_t)w * (16 * 128);
#pragma unroll
  for (int n = 0; n < 8; ++n)
#pragma unroll
    for (int r = 0; r < 4; ++r)
      po[(size_t)(lgrp * 4 + r) * 128 + n * 16 + lrow] = f2b(o[n][r]);
  if (lrow == 0) {
#pragma unroll
    for (int r = 0; r < 4; ++r) {
      pm[(size_t)w * 16 + lgrp * 4 + r] = m[r];
      pl[(size_t)w * 16 + lgrp * 4 + r] = l[r];
    }
  }
}

// ------------- combine split-KV partials -------------
__global__ __launch_bounds__(256) void combine_kernel(const unsigned short* __restrict__ pO,
                                                      const float* __restrict__ pm,
                                                      const float* __restrict__ pl,
                                                      float* __restrict__ out) {
  const int tile = blockIdx.x;      // 0..1023
  const int b = tile >> 7;
  const int j = tile & 127;
  const int a = j >> 4;
  const int nseg = a + 1;
  const int slot0 = b * SLOTS_PER_B + 8 * a * (a + 1) + (j & 15) * (a + 1);

  __shared__ float fac[8][16];
  const int t = threadIdx.x;
  if (t < 16) {
    float M = -1e30f;
    for (int s = 0; s < nseg; ++s) M = fmaxf(M, pm[(size_t)(slot0 + s) * 16 + t]);
    float L = 0.f;
    for (int s = 0; s < nseg; ++s) L += pl[(size_t)(slot0 + s) * 16 + t] * exp2f(pm[(size_t)(slot0 + s) * 16 + t] - M);
    float inv = 1.0f / L;
    for (int s = 0; s < nseg; ++s) fac[s][t] = exp2f(pm[(size_t)(slot0 + s) * 16 + t] - M) * inv;
  }
  __syncthreads();

#pragma unroll
  for (int pass = 0; pass < 2; ++pass) {
    int i4 = pass * 256 + t;        // 0..511 float4s (16 rows x 32 float4/row)
    int row = i4 >> 5;
    int c4 = i4 & 31;
    float4 acc = make_float4(0.f, 0.f, 0.f, 0.f);
    for (int s = 0; s < nseg; ++s) {
      const ushort4 u = reinterpret_cast<const ushort4*>(pO + (size_t)(slot0 + s) * 2048 + row * 128)[c4];
      float f = fac[s][row];
      acc.x += b2f(u.x) * f;
      acc.y += b2f(u.y) * f;
      acc.z += b2f(u.z) * f;
      acc.w += b2f(u.w) * f;
    }
    reinterpret_cast<float4*>(out + ((size_t)b * Tq + j * 16 + row) * Dq)[c4] = acc;
  }
}

extern "C" void kernel_launch(void* const* d_in, const int* in_sizes, int n_in,
                              void* d_out, int out_size, void* d_ws, size_t ws_size,
                              hipStream_t stream) {
  // setup_inputs order: x, Wk, Wq, Wv
  const float* x  = (const float*)d_in[0];
  const float* Wk = (const float*)d_in[1];
  const float* Wq = (const float*)d_in[2];
  const float* Wv = (const float*)d_in[3];
  float* out = (float*)d_out;

  // workspace layout (bf16 elements): x | Wt[3][D][E] | q | k | vT   (~46 MB)
  unsigned short* xb = (unsigned short*)d_ws;
  unsigned short* wt = xb + (size_t)Bq * Tq * Eq;
  unsigned short* qb = wt + (size_t)3 * Dq * Eq;
  unsigned short* kb = qb + (size_t)Bq * Tq * Dq;
  unsigned short* vb = kb + (size_t)Bq * Tq * Dq;
  // split-KV partials alias the xb region (xb is dead after proj_kernel):
  // pO: 4608*2048 bf16 = 18.9 MB, pm/pl: 0.6 MB  (< 33.5 MB)
  unsigned short* pO = xb;
  float* pm = (float*)(xb + (size_t)NSLOT * 16 * 128);
  float* pl = pm + (size_t)NSLOT * 16;

  cast_x_kernel<<<2048, 256, 0, stream>>>(x, xb, Bq * Tq * Eq / 4);
  prep_w_kernel<<<512, 256, 0, stream>>>(Wq, Wk, Wv, wt);
  proj_kernel<<<dim3(Bq * Tq / 64, 3), 256, 0, stream>>>(xb, wt, qb, kb, vb);
  attn_kernel<<<NSLOT / 4, 256, 0, stream>>>(qb, kb, vb, pO, pm, pl);
  combine_kernel<<<Bq * Tq / 16, 256, 0, stream>>>(pO, pm, pl, out);
}

// Round 3
// 173.943 us; speedup vs baseline: 1.2004x; 1.1770x over previous
//
#include <hip/hip_runtime.h>
#include <hip/hip_bf16.h>
#include <stdint.h>

// Problem constants (SelfAttentionHead): B=8, T=2048, E=1024, D=128
#define Bq 8
#define Tq 2048
#define Eq 1024
#define Dq 128
#define BLOCKS_PER_B 144          // sum_{g=0..31} ceil((g+1)/4), LSEG=256
#define NBLK (Bq * BLOCKS_PER_B)  // 1152

typedef __attribute__((ext_vector_type(8))) short short8;   // 8 x bf16 (4 VGPR) MFMA frag
typedef __attribute__((ext_vector_type(4))) float f32x4;    // MFMA accumulator

__device__ __forceinline__ unsigned short f2b(float f) {
  __hip_bfloat16 h = __float2bfloat16(f);   // RNE
  return __builtin_bit_cast(unsigned short, h);
}
__device__ __forceinline__ float b2f(unsigned short u) {
  unsigned int x = ((unsigned int)u) << 16;
  return __builtin_bit_cast(float, x);
}
__device__ __forceinline__ void gload16(const void* g, void* l) {
  __builtin_amdgcn_global_load_lds(
      (const __attribute__((address_space(1))) unsigned int*)g,
      (__attribute__((address_space(3))) unsigned int*)l, 16, 0, 0);
}

// ------------- weights: transpose + cast -> wt[p][d][e] = W_p[e][d]; p: 0=Wq 1=Wk 2=Wv -------------
__global__ void prep_w_kernel(const float* __restrict__ wq, const float* __restrict__ wk,
                              const float* __restrict__ wv, unsigned short* __restrict__ wt) {
  int stride = gridDim.x * blockDim.x;
  const int total = 3 * Dq * Eq;
  for (int o = blockIdx.x * blockDim.x + threadIdx.x; o < total; o += stride) {
    int p = o / (Dq * Eq);
    int r = o - p * (Dq * Eq);
    int d = r / Eq;
    int e = r - d * Eq;
    const float* w = (p == 0) ? wq : (p == 1) ? wk : wv;
    wt[o] = f2b(w[e * Dq + d]);
  }
}

// ------------- fused projections: x(f32) @ {Wq,Wk,Wv} -> q,k (row-major bf16), vT ([B][D][T]) -------------
// 256 blocks x 512 threads (8 waves, 4x2). Block = 64 rows; wave = 16 rows x 64 cols, all 3 mats.
__global__ __launch_bounds__(512) void proj3_kernel(const float* __restrict__ x,
                                                    const unsigned short* __restrict__ wt,
                                                    unsigned short* __restrict__ qo,
                                                    unsigned short* __restrict__ ko,
                                                    unsigned short* __restrict__ vo) {
  const int lane = threadIdx.x & 63;
  const int wid  = threadIdx.x >> 6;
  const int wm   = wid >> 1, wn = wid & 1;
  const int row0 = blockIdx.x * 64 + wm * 16;
  const int col0 = wn * 64;
  const int lrow = lane & 15;
  const int lk8  = (lane >> 4) * 8;

  f32x4 acc[3][4];
#pragma unroll
  for (int p = 0; p < 3; ++p)
#pragma unroll
    for (int n = 0; n < 4; ++n) acc[p][n] = (f32x4){0.f, 0.f, 0.f, 0.f};

  for (int ks = 0; ks < Eq; ks += 32) {
    const float* xr = x + (size_t)(row0 + lrow) * Eq + ks + lk8;
    float4 f0 = *reinterpret_cast<const float4*>(xr);
    float4 f1 = *reinterpret_cast<const float4*>(xr + 4);
    short8 a;
    a[0] = (short)f2b(f0.x); a[1] = (short)f2b(f0.y); a[2] = (short)f2b(f0.z); a[3] = (short)f2b(f0.w);
    a[4] = (short)f2b(f1.x); a[5] = (short)f2b(f1.y); a[6] = (short)f2b(f1.z); a[7] = (short)f2b(f1.w);
#pragma unroll
    for (int p = 0; p < 3; ++p)
#pragma unroll
      for (int n = 0; n < 4; ++n) {
        short8 b = *reinterpret_cast<const short8*>(wt + (size_t)p * Dq * Eq +
                                                    (size_t)(col0 + n * 16 + lrow) * Eq + ks + lk8);
        acc[p][n] = __builtin_amdgcn_mfma_f32_16x16x32_bf16(a, b, acc[p][n], 0, 0, 0);
      }
  }

  const int rg   = (lane >> 4) * 4;
  const int lcol = lane & 15;
#pragma unroll
  for (int p = 0; p < 3; ++p) {
    if (p < 2) {
      unsigned short* out = (p == 0) ? qo : ko;
#pragma unroll
      for (int n = 0; n < 4; ++n)
#pragma unroll
        for (int r = 0; r < 4; ++r)
          out[(size_t)(row0 + rg + r) * Dq + col0 + n * 16 + lcol] = f2b(acc[p][n][r]);
    } else {
#pragma unroll
      for (int n = 0; n < 4; ++n)
#pragma unroll
        for (int r = 0; r < 4; ++r) {
          int trow = row0 + rg + r;
          int bb = trow >> 11;
          int t  = trow & (Tq - 1);
          vo[(size_t)bb * Dq * Tq + (size_t)(col0 + n * 16 + lcol) * Tq + t] = f2b(acc[p][n][r]);
        }
    }
  }
}

// ------------- split-KV causal flash attention, block-cooperative LDS staging -------------
// Block (256 thr = 4 waves) = (batch b, 64-row Q group g, KV segment s of 256).
// Wave w owns rows 64g+16w..+15. Per 64-col step: cooperative K/V tile DMA to LDS
// (double-buffered, source-swizzled), then per-wave QK/softmax/PV from LDS.
__global__ __launch_bounds__(256) void attn_kernel(const unsigned short* __restrict__ q,
                                                   const unsigned short* __restrict__ k,
                                                   const unsigned short* __restrict__ vT,
                                                   unsigned short* __restrict__ pO,
                                                   float* __restrict__ pm,
                                                   float* __restrict__ pl) {
  __shared__ __align__(16) char kbuf[2][16384];            // K tile: 64 rows x 256B
  __shared__ __align__(16) char vbuf[2][16384];            // V tile: 128 d-rows x 128B
  __shared__ __align__(16) unsigned short pbuf[4][1024];   // per-wave P tile 16x64

  const int lane = threadIdx.x & 63;
  const int w    = threadIdx.x >> 6;
  const int bx   = blockIdx.x;
  const int b    = bx / BLOCKS_PER_B;
  int rm = bx - b * BLOCKS_PER_B;
  int g = 0, s = 0;
#pragma unroll
  for (int c = 1; c <= 8; ++c) {        // groups 4(c-1)..4c-1 have c segments each
    int cnt = 4 * c;
    if (rm < cnt) { g = 4 * (c - 1) + rm / c; s = rm % c; break; }
    rm -= cnt;
  }
  const int kv0      = 256 * s;
  const int kend_blk = min(kv0 + 256, 64 * g + 64);
  const int qb0      = 64 * g + 16 * w;
  const int kend_w   = qb0 + 16;

  const int lrow = lane & 15;
  const int lgrp = lane >> 4;
  const int lk8  = lgrp * 8;
  const float kscale = 0.08838834764831845f * 1.44269504088896340736f; // D^-0.5 * log2(e)
  unsigned short* pb = pbuf[w];
  const char* kgbase = (const char*)(k + (size_t)b * Tq * Dq);
  const char* vgbase = (const char*)(vT + (size_t)b * Dq * Tq);

  // cooperative stage of one 64-col K/V tile pair into buffer `bufi`
  auto STAGE = [&](int bufi, int kvb) {
    const char* ksrc = kgbase + (size_t)kvb * 256;   // contiguous 16KB
    char* kl = kbuf[bufi];
    char* vl = vbuf[bufi];
    const int kvb2 = kvb * 2;
#pragma unroll
    for (int i = 0; i < 4; ++i) {
      int y  = i * 4096 + w * 1024;                  // wave-uniform LDS byte base
      int yl = y + lane * 16;                        // this lane's dest byte
      int src = yl ^ ((((yl >> 8) & 7)) << 4);       // inverse swizzle on source
      gload16(ksrc + src, kl + y);
    }
#pragma unroll
    for (int i = 0; i < 4; ++i) {
      int y  = i * 4096 + w * 1024;
      int yl = y + lane * 16;
      int d  = yl >> 7;
      int src = d * 4096 + kvb2 + ((yl & 127) ^ ((d & 7) << 4));
      gload16(vgbase + src, vl + y);
    }
  };

  // Q fragments (registers)
  short8 qf[4];
  const unsigned short* qrow = q + ((size_t)b * Tq + qb0 + lrow) * Dq;
#pragma unroll
  for (int kc = 0; kc < 4; ++kc)
    qf[kc] = *reinterpret_cast<const short8*>(qrow + kc * 32 + lk8);

  f32x4 o[8];
#pragma unroll
  for (int n = 0; n < 8; ++n) o[n] = (f32x4){0.f, 0.f, 0.f, 0.f};
  float m[4], l[4];
#pragma unroll
  for (int r = 0; r < 4; ++r) { m[r] = -1e30f; l[r] = 0.f; }
  const int rowg = qb0 + lgrp * 4;

  STAGE(0, kv0);
  const int nsteps = (kend_blk - kv0) >> 6;
  __syncthreads();                                   // buf0 ready (vmcnt(0)+barrier)

  for (int t = 0; t < nsteps; ++t) {
    const int kvb = kv0 + (t << 6);
    const int cur = t & 1;
    if (t + 1 < nsteps) STAGE(cur ^ 1, kvb + 64);    // prefetch next tile (in flight during compute)

    if (kvb < kend_w) {
      const char* kbp = kbuf[cur];
      // ---- QK^T: 64 score cols from LDS ----
      f32x4 sf[4];
#pragma unroll
      for (int n = 0; n < 4; ++n) sf[n] = (f32x4){0.f, 0.f, 0.f, 0.f};
#pragma unroll
      for (int kc = 0; kc < 4; ++kc)
#pragma unroll
        for (int n = 0; n < 4; ++n) {
          int u = (n * 16 + lrow) * 256 + kc * 64 + lgrp * 16;
          short8 kf = *reinterpret_cast<const short8*>(kbp + (u ^ ((lrow & 7) << 4)));
          sf[n] = __builtin_amdgcn_mfma_f32_16x16x32_bf16(qf[kc], kf, sf[n], 0, 0, 0);
        }

      // ---- scale + causal mask + online softmax ----
      const bool needmask = (kvb + 64 > qb0);
      float p[4][4], mx[4];
#pragma unroll
      for (int r = 0; r < 4; ++r) mx[r] = -1e30f;
#pragma unroll
      for (int n = 0; n < 4; ++n)
#pragma unroll
        for (int r = 0; r < 4; ++r) {
          float aa = sf[n][r] * kscale;
          if (needmask && (kvb + n * 16 + lrow > rowg + r)) aa = -1e30f;
          p[n][r] = aa;
          mx[r] = fmaxf(mx[r], aa);
        }
#pragma unroll
      for (int off = 1; off < 16; off <<= 1)
#pragma unroll
        for (int r = 0; r < 4; ++r) mx[r] = fmaxf(mx[r], __shfl_xor(mx[r], off, 64));

      float alpha[4], sm[4];
#pragma unroll
      for (int r = 0; r < 4; ++r) {
        float mn = fmaxf(m[r], mx[r]);
        alpha[r] = exp2f(m[r] - mn);
        m[r] = mn;
        sm[r] = 0.f;
#pragma unroll
        for (int n = 0; n < 4; ++n) {
          p[n][r] = exp2f(p[n][r] - mn);
          sm[r] += p[n][r];
        }
      }
#pragma unroll
      for (int off = 1; off < 16; off <<= 1)
#pragma unroll
        for (int r = 0; r < 4; ++r) sm[r] += __shfl_xor(sm[r], off, 64);
#pragma unroll
      for (int r = 0; r < 4; ++r) l[r] = l[r] * alpha[r] + sm[r];
#pragma unroll
      for (int n = 0; n < 8; ++n)
#pragma unroll
        for (int r = 0; r < 4; ++r) o[n][r] *= alpha[r];

      // ---- P (score layout) -> per-wave LDS (swizzled) -> A-operand fragments ----
#pragma unroll
      for (int n = 0; n < 4; ++n)
#pragma unroll
        for (int r = 0; r < 4; ++r) {
          int row = lgrp * 4 + r;
          int byte = row * 128 + (n * 16 + lrow) * 2;
          byte ^= (row & 7) << 4;
          *reinterpret_cast<unsigned short*>(reinterpret_cast<char*>(pb) + byte) = f2b(p[n][r]);
        }
      asm volatile("s_waitcnt lgkmcnt(0)" ::: "memory");
      __builtin_amdgcn_sched_barrier(0);
      int rbyte0 = (lrow * 128 + lgrp * 16) ^ ((lrow & 7) << 4);
      int rbyte1 = (lrow * 128 + 64 + lgrp * 16) ^ ((lrow & 7) << 4);
      short8 pf0 = *reinterpret_cast<const short8*>(reinterpret_cast<char*>(pb) + rbyte0);
      short8 pf1 = *reinterpret_cast<const short8*>(reinterpret_cast<char*>(pb) + rbyte1);

      // ---- PV: O += P @ V from LDS ----
      const char* vbp = vbuf[cur];
#pragma unroll
      for (int n = 0; n < 8; ++n) {
        int u0 = (n * 16 + lrow) * 128 + lgrp * 16;
        short8 vf0 = *reinterpret_cast<const short8*>(vbp + (u0 ^ ((lrow & 7) << 4)));
        short8 vf1 = *reinterpret_cast<const short8*>(vbp + ((u0 + 64) ^ ((lrow & 7) << 4)));
        o[n] = __builtin_amdgcn_mfma_f32_16x16x32_bf16(pf0, vf0, o[n], 0, 0, 0);
        o[n] = __builtin_amdgcn_mfma_f32_16x16x32_bf16(pf1, vf1, o[n], 0, 0, 0);
      }
    }
    __syncthreads();   // next buf ready + all waves done reading cur
  }

  // ---- store partial (unnormalized O bf16, running m/l f32); slot == blockIdx.x ----
  unsigned short* po = pO + (size_t)bx * (64 * 128) + (size_t)(16 * w) * 128;
#pragma unroll
  for (int n = 0; n < 8; ++n)
#pragma unroll
    for (int r = 0; r < 4; ++r)
      po[(size_t)(lgrp * 4 + r) * 128 + n * 16 + lrow] = f2b(o[n][r]);
  if (lrow == 0) {
#pragma unroll
    for (int r = 0; r < 4; ++r) {
      pm[(size_t)bx * 64 + 16 * w + lgrp * 4 + r] = m[r];
      pl[(size_t)bx * 64 + 16 * w + lgrp * 4 + r] = l[r];
    }
  }
}

// ------------- combine split-KV partials: 256 blocks, each 64 rows x 128 cols -------------
__global__ __launch_bounds__(256) void combine_kernel(const unsigned short* __restrict__ pO,
                                                      const float* __restrict__ pm,
                                                      const float* __restrict__ pl,
                                                      float* __restrict__ out) {
  const int tile = blockIdx.x;      // 0..255: (b, g)
  const int b = tile >> 5;
  const int g = tile & 31;
  const int qq = g >> 2, rr = g & 3;
  const int nseg = qq + 1;
  const int slot0 = b * BLOCKS_PER_B + g + 2 * qq * (qq - 1) + qq * rr;

  __shared__ float fac[8][64];
  const int t = threadIdx.x;
  if (t < 64) {
    float M = -1e30f;
    for (int s = 0; s < nseg; ++s) M = fmaxf(M, pm[(size_t)(slot0 + s) * 64 + t]);
    float L = 0.f;
    for (int s = 0; s < nseg; ++s)
      L += pl[(size_t)(slot0 + s) * 64 + t] * exp2f(pm[(size_t)(slot0 + s) * 64 + t] - M);
    float inv = 1.0f / L;
    for (int s = 0; s < nseg; ++s)
      fac[s][t] = exp2f(pm[(size_t)(slot0 + s) * 64 + t] - M) * inv;
  }
  __syncthreads();

#pragma unroll
  for (int pass = 0; pass < 8; ++pass) {
    int i4 = pass * 256 + t;        // 0..2047 float4s (64 rows x 32 float4/row)
    int row = i4 >> 5;
    int c4 = i4 & 31;
    float4 acc = make_float4(0.f, 0.f, 0.f, 0.f);
    for (int s = 0; s < nseg; ++s) {
      const ushort4 u = reinterpret_cast<const ushort4*>(pO + (size_t)(slot0 + s) * 8192 + row * 128)[c4];
      float f = fac[s][row];
      acc.x += b2f(u.x) * f;
      acc.y += b2f(u.y) * f;
      acc.z += b2f(u.z) * f;
      acc.w += b2f(u.w) * f;
    }
    reinterpret_cast<float4*>(out + ((size_t)b * Tq + g * 64 + row) * Dq)[c4] = acc;
  }
}

extern "C" void kernel_launch(void* const* d_in, const int* in_sizes, int n_in,
                              void* d_out, int out_size, void* d_ws, size_t ws_size,
                              hipStream_t stream) {
  // setup_inputs order: x, Wk, Wq, Wv
  const float* x  = (const float*)d_in[0];
  const float* Wk = (const float*)d_in[1];
  const float* Wq = (const float*)d_in[2];
  const float* Wv = (const float*)d_in[3];
  float* out = (float*)d_out;

  // workspace (bf16 elems): wt[3][D][E] | q | k | vT | pO | pm | pl  (~33 MB)
  unsigned short* wt = (unsigned short*)d_ws;
  unsigned short* qb = wt + (size_t)3 * Dq * Eq;
  unsigned short* kb = qb + (size_t)Bq * Tq * Dq;
  unsigned short* vb = kb + (size_t)Bq * Tq * Dq;
  unsigned short* pO = vb + (size_t)Bq * Tq * Dq;
  float* pm = (float*)(pO + (size_t)NBLK * 64 * 128);
  float* pl = pm + (size_t)NBLK * 64;

  prep_w_kernel<<<512, 256, 0, stream>>>(Wq, Wk, Wv, wt);
  proj3_kernel<<<Bq * Tq / 64, 512, 0, stream>>>(x, wt, qb, kb, vb);
  attn_kernel<<<NBLK, 256, 0, stream>>>(qb, kb, vb, pO, pm, pl);
  combine_kernel<<<Bq * Tq / 64, 256, 0, stream>>>(pO, pm, pl, out);
}

// Round 4
// 104.150 us; speedup vs baseline: 2.0049x; 1.6701x over previous
//
#include <hip/hip_runtime.h>
#include <hip/hip_bf16.h>
#include <stdint.h>

// Problem constants (SelfAttentionHead): B=8, T=2048, E=1024, D=128
#define Bq 8
#define Tq 2048
#define Eq 1024
#define Dq 128
#define BLOCKS_PER_B 144          // sum_{g=0..31} ceil((g+1)/4), LSEG=256
#define NBLK (Bq * BLOCKS_PER_B)  // 1152

typedef __attribute__((ext_vector_type(8))) short short8;   // 8 x bf16 (4 VGPR) MFMA frag
typedef __attribute__((ext_vector_type(4))) float f32x4;    // MFMA accumulator

__device__ __forceinline__ unsigned short f2b(float f) {
  __hip_bfloat16 h = __float2bfloat16(f);   // RNE
  return __builtin_bit_cast(unsigned short, h);
}
__device__ __forceinline__ float b2f(unsigned short u) {
  unsigned int x = ((unsigned int)u) << 16;
  return __builtin_bit_cast(float, x);
}
__device__ __forceinline__ void gload16(const void* g, void* l) {
  __builtin_amdgcn_global_load_lds(
      (const __attribute__((address_space(1))) unsigned int*)g,
      (__attribute__((address_space(3))) unsigned int*)l, 16, 0, 0);
}

// ------------- weights: transpose + cast via LDS -> wt[p][d][e] = W_p[e][d]; p: 0=Wq 1=Wk 2=Wv -------------
// 48 blocks: (p, 64-wide e-chunk). Coalesced f32 reads, coalesced 8B bf16 writes.
__global__ __launch_bounds__(256) void prep_w_kernel(const float* __restrict__ wq,
                                                     const float* __restrict__ wk,
                                                     const float* __restrict__ wv,
                                                     unsigned short* __restrict__ wt) {
  __shared__ float tile[64][129];
  const int p  = blockIdx.x >> 4;
  const int e0 = (blockIdx.x & 15) * 64;
  const float* w = (p == 0) ? wq : (p == 1) ? wk : wv;
  const int tid = threadIdx.x;
#pragma unroll
  for (int i = 0; i < 32; ++i) {
    int idx = i * 256 + tid;            // 0..8191
    int r = idx >> 7, c = idx & 127;
    tile[r][c] = w[(size_t)(e0 + r) * Dq + c];
  }
  __syncthreads();
  const int d = tid >> 1;
  const int es = (tid & 1) * 32;
  unsigned short* dst = wt + (size_t)p * Dq * Eq + (size_t)d * Eq + e0 + es;
#pragma unroll
  for (int c4 = 0; c4 < 8; ++c4) {
    ushort4 u;
    u.x = f2b(tile[es + c4 * 4 + 0][d]);
    u.y = f2b(tile[es + c4 * 4 + 1][d]);
    u.z = f2b(tile[es + c4 * 4 + 2][d]);
    u.w = f2b(tile[es + c4 * 4 + 3][d]);
    *reinterpret_cast<ushort4*>(dst + c4 * 4) = u;
  }
}

// ------------- fused projections, LDS-staged (m97-style 2-phase) -------------
// Grid 768 = 256 row-tiles x 3 mats (p innermost -> x-tile L2 reuse). 256 thr = 4 waves (2x2).
// Block tile: 64 rows x 128 cols (full D), BK=32, K=1024. x staged as f32 + in-reg bf16 convert.
__global__ __launch_bounds__(256) void proj3_kernel(const float* __restrict__ x,
                                                    const unsigned short* __restrict__ wt,
                                                    unsigned short* __restrict__ qo,
                                                    unsigned short* __restrict__ ko,
                                                    unsigned short* __restrict__ vo) {
  __shared__ __align__(16) char As[2][8192];   // 64 rows x 32 f32 (128B), XOR-swizzled
  __shared__ __align__(16) char Bs[2][8192];   // 128 cols x 32 bf16 (64B), XOR-swizzled

  const int bid  = blockIdx.x;
  const int p    = bid % 3;                    // 0=q 1=k 2=v
  const int rt   = bid / 3;
  const int row0 = rt * 64;
  const int lane = threadIdx.x & 63;
  const int w    = threadIdx.x >> 6;
  const int wm   = w >> 1, wn = w & 1;
  const int lrow = lane & 15;
  const int lgrp = lane >> 4;
  const char* xbyte  = (const char*)x;
  const char* wtbyte = (const char*)(wt + (size_t)p * Dq * Eq);

  auto STAGE = [&](int bufi, int ks) {
#pragma unroll
    for (int i = 0; i < 2; ++i) {              // A: 64 rows x 128B
      int y  = i * 4096 + w * 1024;            // wave-uniform LDS base
      int yl = y + lane * 16;
      int row = yl >> 7, j = yl & 127;
      gload16(xbyte + (size_t)(row0 + row) * 4096 + ks * 4 + (j ^ ((row & 7) << 4)),
              As[bufi] + y);
    }
#pragma unroll
    for (int i = 0; i < 2; ++i) {              // B: 128 cols x 64B
      int y  = i * 4096 + w * 1024;
      int yl = y + lane * 16;
      int col = yl >> 6, j = yl & 63;
      gload16(wtbyte + (size_t)col * 2048 + ks * 2 + (j ^ (((col >> 1) & 3) << 4)),
              Bs[bufi] + y);
    }
  };

  f32x4 acc[2][4];
#pragma unroll
  for (int m = 0; m < 2; ++m)
#pragma unroll
    for (int n = 0; n < 4; ++n) acc[m][n] = (f32x4){0.f, 0.f, 0.f, 0.f};

  STAGE(0, 0);
  __syncthreads();

  for (int t = 0; t < 32; ++t) {
    const int cur = t & 1;
    if (t < 31) STAGE(cur ^ 1, (t + 1) * 32);  // prefetch in flight during compute

    const char* Ab = As[cur];
    const char* Bb = Bs[cur];
    short8 af[2];
#pragma unroll
    for (int m = 0; m < 2; ++m) {
      int ar = wm * 32 + m * 16 + lrow;
      int sw = (ar & 7) << 4;
      f32x4 a0 = *reinterpret_cast<const f32x4*>(Ab + ar * 128 + ((lgrp * 32) ^ sw));
      f32x4 a1 = *reinterpret_cast<const f32x4*>(Ab + ar * 128 + ((lgrp * 32 + 16) ^ sw));
      short8 v;
      v[0] = (short)f2b(a0[0]); v[1] = (short)f2b(a0[1]);
      v[2] = (short)f2b(a0[2]); v[3] = (short)f2b(a0[3]);
      v[4] = (short)f2b(a1[0]); v[5] = (short)f2b(a1[1]);
      v[6] = (short)f2b(a1[2]); v[7] = (short)f2b(a1[3]);
      af[m] = v;
    }
    short8 bf_[4];
#pragma unroll
    for (int n = 0; n < 4; ++n) {
      int bc = wn * 64 + n * 16 + lrow;
      bf_[n] = *reinterpret_cast<const short8*>(Bb + bc * 64 + ((lgrp * 16) ^ (((bc >> 1) & 3) << 4)));
    }
#pragma unroll
    for (int m = 0; m < 2; ++m)
#pragma unroll
      for (int n = 0; n < 4; ++n)
        acc[m][n] = __builtin_amdgcn_mfma_f32_16x16x32_bf16(af[m], bf_[n], acc[m][n], 0, 0, 0);
    __syncthreads();
  }

  // epilogue: C/D layout col=lane&15, row=(lane>>4)*4+reg
  const int rg   = (lane >> 4) * 4;
  const int lcol = lane & 15;
  if (p < 2) {
    unsigned short* out = (p == 0) ? qo : ko;
#pragma unroll
    for (int m = 0; m < 2; ++m)
#pragma unroll
      for (int n = 0; n < 4; ++n)
#pragma unroll
        for (int r = 0; r < 4; ++r)
          out[(size_t)(row0 + wm * 32 + m * 16 + rg + r) * Dq + wn * 64 + n * 16 + lcol] =
              f2b(acc[m][n][r]);
  } else {
    // store V transposed: vT[b][d][t]
#pragma unroll
    for (int m = 0; m < 2; ++m)
#pragma unroll
      for (int n = 0; n < 4; ++n)
#pragma unroll
        for (int r = 0; r < 4; ++r) {
          int trow = row0 + wm * 32 + m * 16 + rg + r;
          int bb = trow >> 11;
          int t  = trow & (Tq - 1);
          vo[(size_t)bb * Dq * Tq + (size_t)(wn * 64 + n * 16 + lcol) * Tq + t] = f2b(acc[m][n][r]);
        }
  }
}

// ------------- split-KV causal flash attention, block-cooperative LDS staging -------------
// Block (256 thr = 4 waves) = (batch b, 64-row Q group g, KV segment s of 256).
// Wave w owns rows 64g+16w..+15. Per 64-col step: cooperative K/V tile DMA to LDS
// (double-buffered, source-swizzled), then per-wave QK/softmax/PV from LDS.
__global__ __launch_bounds__(256) void attn_kernel(const unsigned short* __restrict__ q,
                                                   const unsigned short* __restrict__ k,
                                                   const unsigned short* __restrict__ vT,
                                                   unsigned short* __restrict__ pO,
                                                   float* __restrict__ pm,
                                                   float* __restrict__ pl) {
  __shared__ __align__(16) char kbuf[2][16384];            // K tile: 64 rows x 256B
  __shared__ __align__(16) char vbuf[2][16384];            // V tile: 128 d-rows x 128B
  __shared__ __align__(16) unsigned short pbuf[4][1024];   // per-wave P tile 16x64

  const int lane = threadIdx.x & 63;
  const int w    = threadIdx.x >> 6;
  const int bx   = blockIdx.x;
  const int b    = bx / BLOCKS_PER_B;
  int rm = bx - b * BLOCKS_PER_B;
  int g = 0, s = 0;
#pragma unroll
  for (int c = 1; c <= 8; ++c) {        // groups 4(c-1)..4c-1 have c segments each
    int cnt = 4 * c;
    if (rm < cnt) { g = 4 * (c - 1) + rm / c; s = rm % c; break; }
    rm -= cnt;
  }
  const int kv0      = 256 * s;
  const int kend_blk = min(kv0 + 256, 64 * g + 64);
  const int qb0      = 64 * g + 16 * w;
  const int kend_w   = qb0 + 16;

  const int lrow = lane & 15;
  const int lgrp = lane >> 4;
  const int lk8  = lgrp * 8;
  const float kscale = 0.08838834764831845f * 1.44269504088896340736f; // D^-0.5 * log2(e)
  unsigned short* pb = pbuf[w];
  const char* kgbase = (const char*)(k + (size_t)b * Tq * Dq);
  const char* vgbase = (const char*)(vT + (size_t)b * Dq * Tq);

  // cooperative stage of one 64-col K/V tile pair into buffer `bufi`
  auto STAGE = [&](int bufi, int kvb) {
    const char* ksrc = kgbase + (size_t)kvb * 256;   // contiguous 16KB
    char* kl = kbuf[bufi];
    char* vl = vbuf[bufi];
    const int kvb2 = kvb * 2;
#pragma unroll
    for (int i = 0; i < 4; ++i) {
      int y  = i * 4096 + w * 1024;                  // wave-uniform LDS byte base
      int yl = y + lane * 16;                        // this lane's dest byte
      int src = yl ^ ((((yl >> 8) & 7)) << 4);       // inverse swizzle on source
      gload16(ksrc + src, kl + y);
    }
#pragma unroll
    for (int i = 0; i < 4; ++i) {
      int y  = i * 4096 + w * 1024;
      int yl = y + lane * 16;
      int d  = yl >> 7;
      int src = d * 4096 + kvb2 + ((yl & 127) ^ ((d & 7) << 4));
      gload16(vgbase + src, vl + y);
    }
  };

  // Q fragments (registers)
  short8 qf[4];
  const unsigned short* qrow = q + ((size_t)b * Tq + qb0 + lrow) * Dq;
#pragma unroll
  for (int kc = 0; kc < 4; ++kc)
    qf[kc] = *reinterpret_cast<const short8*>(qrow + kc * 32 + lk8);

  f32x4 o[8];
#pragma unroll
  for (int n = 0; n < 8; ++n) o[n] = (f32x4){0.f, 0.f, 0.f, 0.f};
  float m[4], l[4];
#pragma unroll
  for (int r = 0; r < 4; ++r) { m[r] = -1e30f; l[r] = 0.f; }
  const int rowg = qb0 + lgrp * 4;

  STAGE(0, kv0);
  const int nsteps = (kend_blk - kv0) >> 6;
  __syncthreads();                                   // buf0 ready (vmcnt(0)+barrier)

  for (int t = 0; t < nsteps; ++t) {
    const int kvb = kv0 + (t << 6);
    const int cur = t & 1;
    if (t + 1 < nsteps) STAGE(cur ^ 1, kvb + 64);    // prefetch next tile (in flight during compute)

    if (kvb < kend_w) {
      const char* kbp = kbuf[cur];
      // ---- QK^T: 64 score cols from LDS ----
      f32x4 sf[4];
#pragma unroll
      for (int n = 0; n < 4; ++n) sf[n] = (f32x4){0.f, 0.f, 0.f, 0.f};
#pragma unroll
      for (int kc = 0; kc < 4; ++kc)
#pragma unroll
        for (int n = 0; n < 4; ++n) {
          int u = (n * 16 + lrow) * 256 + kc * 64 + lgrp * 16;
          short8 kf = *reinterpret_cast<const short8*>(kbp + (u ^ ((lrow & 7) << 4)));
          sf[n] = __builtin_amdgcn_mfma_f32_16x16x32_bf16(qf[kc], kf, sf[n], 0, 0, 0);
        }

      // ---- scale + causal mask + online softmax ----
      const bool needmask = (kvb + 64 > qb0);
      float p[4][4], mx[4];
#pragma unroll
      for (int r = 0; r < 4; ++r) mx[r] = -1e30f;
#pragma unroll
      for (int n = 0; n < 4; ++n)
#pragma unroll
        for (int r = 0; r < 4; ++r) {
          float aa = sf[n][r] * kscale;
          if (needmask && (kvb + n * 16 + lrow > rowg + r)) aa = -1e30f;
          p[n][r] = aa;
          mx[r] = fmaxf(mx[r], aa);
        }
#pragma unroll
      for (int off = 1; off < 16; off <<= 1)
#pragma unroll
        for (int r = 0; r < 4; ++r) mx[r] = fmaxf(mx[r], __shfl_xor(mx[r], off, 64));

      float alpha[4], sm[4];
#pragma unroll
      for (int r = 0; r < 4; ++r) {
        float mn = fmaxf(m[r], mx[r]);
        alpha[r] = exp2f(m[r] - mn);
        m[r] = mn;
        sm[r] = 0.f;
#pragma unroll
        for (int n = 0; n < 4; ++n) {
          p[n][r] = exp2f(p[n][r] - mn);
          sm[r] += p[n][r];
        }
      }
#pragma unroll
      for (int off = 1; off < 16; off <<= 1)
#pragma unroll
        for (int r = 0; r < 4; ++r) sm[r] += __shfl_xor(sm[r], off, 64);
#pragma unroll
      for (int r = 0; r < 4; ++r) l[r] = l[r] * alpha[r] + sm[r];
#pragma unroll
      for (int n = 0; n < 8; ++n)
#pragma unroll
        for (int r = 0; r < 4; ++r) o[n][r] *= alpha[r];

      // ---- P (score layout) -> per-wave LDS (swizzled) -> A-operand fragments ----
#pragma unroll
      for (int n = 0; n < 4; ++n)
#pragma unroll
        for (int r = 0; r < 4; ++r) {
          int row = lgrp * 4 + r;
          int byte = row * 128 + (n * 16 + lrow) * 2;
          byte ^= (row & 7) << 4;
          *reinterpret_cast<unsigned short*>(reinterpret_cast<char*>(pb) + byte) = f2b(p[n][r]);
        }
      asm volatile("s_waitcnt lgkmcnt(0)" ::: "memory");
      __builtin_amdgcn_sched_barrier(0);
      int rbyte0 = (lrow * 128 + lgrp * 16) ^ ((lrow & 7) << 4);
      int rbyte1 = (lrow * 128 + 64 + lgrp * 16) ^ ((lrow & 7) << 4);
      short8 pf0 = *reinterpret_cast<const short8*>(reinterpret_cast<char*>(pb) + rbyte0);
      short8 pf1 = *reinterpret_cast<const short8*>(reinterpret_cast<char*>(pb) + rbyte1);

      // ---- PV: O += P @ V from LDS ----
      const char* vbp = vbuf[cur];
#pragma unroll
      for (int n = 0; n < 8; ++n) {
        int u0 = (n * 16 + lrow) * 128 + lgrp * 16;
        short8 vf0 = *reinterpret_cast<const short8*>(vbp + (u0 ^ ((lrow & 7) << 4)));
        short8 vf1 = *reinterpret_cast<const short8*>(vbp + ((u0 + 64) ^ ((lrow & 7) << 4)));
        o[n] = __builtin_amdgcn_mfma_f32_16x16x32_bf16(pf0, vf0, o[n], 0, 0, 0);
        o[n] = __builtin_amdgcn_mfma_f32_16x16x32_bf16(pf1, vf1, o[n], 0, 0, 0);
      }
    }
    __syncthreads();   // next buf ready + all waves done reading cur
  }

  // ---- store partial (unnormalized O bf16, running m/l f32); slot == blockIdx.x ----
  unsigned short* po = pO + (size_t)bx * (64 * 128) + (size_t)(16 * w) * 128;
#pragma unroll
  for (int n = 0; n < 8; ++n)
#pragma unroll
    for (int r = 0; r < 4; ++r)
      po[(size_t)(lgrp * 4 + r) * 128 + n * 16 + lrow] = f2b(o[n][r]);
  if (lrow == 0) {
#pragma unroll
    for (int r = 0; r < 4; ++r) {
      pm[(size_t)bx * 64 + 16 * w + lgrp * 4 + r] = m[r];
      pl[(size_t)bx * 64 + 16 * w + lgrp * 4 + r] = l[r];
    }
  }
}

// ------------- combine split-KV partials: 256 blocks, each 64 rows x 128 cols -------------
__global__ __launch_bounds__(256) void combine_kernel(const unsigned short* __restrict__ pO,
                                                      const float* __restrict__ pm,
                                                      const float* __restrict__ pl,
                                                      float* __restrict__ out) {
  const int tile = blockIdx.x;      // 0..255: (b, g)
  const int b = tile >> 5;
  const int g = tile & 31;
  const int qq = g >> 2, rr = g & 3;
  const int nseg = qq + 1;
  const int slot0 = b * BLOCKS_PER_B + g + 2 * qq * (qq - 1) + qq * rr;

  __shared__ float fac[8][64];
  const int t = threadIdx.x;
  if (t < 64) {
    float M = -1e30f;
    for (int s = 0; s < nseg; ++s) M = fmaxf(M, pm[(size_t)(slot0 + s) * 64 + t]);
    float L = 0.f;
    for (int s = 0; s < nseg; ++s)
      L += pl[(size_t)(slot0 + s) * 64 + t] * exp2f(pm[(size_t)(slot0 + s) * 64 + t] - M);
    float inv = 1.0f / L;
    for (int s = 0; s < nseg; ++s)
      fac[s][t] = exp2f(pm[(size_t)(slot0 + s) * 64 + t] - M) * inv;
  }
  __syncthreads();

#pragma unroll
  for (int pass = 0; pass < 8; ++pass) {
    int i4 = pass * 256 + t;        // 0..2047 float4s (64 rows x 32 float4/row)
    int row = i4 >> 5;
    int c4 = i4 & 31;
    float4 acc = make_float4(0.f, 0.f, 0.f, 0.f);
    for (int s = 0; s < nseg; ++s) {
      const ushort4 u = reinterpret_cast<const ushort4*>(pO + (size_t)(slot0 + s) * 8192 + row * 128)[c4];
      float f = fac[s][row];
      acc.x += b2f(u.x) * f;
      acc.y += b2f(u.y) * f;
      acc.z += b2f(u.z) * f;
      acc.w += b2f(u.w) * f;
    }
    reinterpret_cast<float4*>(out + ((size_t)b * Tq + g * 64 + row) * Dq)[c4] = acc;
  }
}

extern "C" void kernel_launch(void* const* d_in, const int* in_sizes, int n_in,
                              void* d_out, int out_size, void* d_ws, size_t ws_size,
                              hipStream_t stream) {
  // setup_inputs order: x, Wk, Wq, Wv
  const float* x  = (const float*)d_in[0];
  const float* Wk = (const float*)d_in[1];
  const float* Wq = (const float*)d_in[2];
  const float* Wv = (const float*)d_in[3];
  float* out = (float*)d_out;

  // workspace (bf16 elems): wt[3][D][E] | q | k | vT | pO | pm | pl  (~46 MB)
  unsigned short* wt = (unsigned short*)d_ws;
  unsigned short* qb = wt + (size_t)3 * Dq * Eq;
  unsigned short* kb = qb + (size_t)Bq * Tq * Dq;
  unsigned short* vb = kb + (size_t)Bq * Tq * Dq;
  unsigned short* pO = vb + (size_t)Bq * Tq * Dq;
  float* pm = (float*)(pO + (size_t)NBLK * 64 * 128);
  float* pl = pm + (size_t)NBLK * 64;

  prep_w_kernel<<<48, 256, 0, stream>>>(Wq, Wk, Wv, wt);
  proj3_kernel<<<Bq * Tq / 64 * 3, 256, 0, stream>>>(x, wt, qb, kb, vb);
  attn_kernel<<<NBLK, 256, 0, stream>>>(qb, kb, vb, pO, pm, pl);
  combine_kernel<<<Bq * Tq / 64, 256, 0, stream>>>(pO, pm, pl, out);
}